// Round 1
// baseline (738.074 us; speedup 1.0000x reference)
//
#include <hip/hip_runtime.h>

#define B_ 16
#define L_ 4096
#define DK_ 64
#define R_ 4
#define NB_ 64
#define BL_ 64
#define KSTR 68   // LDS row stride in floats (16B-aligned, bank-spread)

// ---------------- Kernel 1: LSH hashing (fp64 dots for argmax stability) ----
__global__ __launch_bounds__(256) void hash_kernel(
    const float* __restrict__ query, const float* __restrict__ rm,
    int* __restrict__ bucket) {
  __shared__ float srm[DK_ * 128];   // [d][rn], rn = r*32+n
  __shared__ double sinv[128];
  int b = blockIdx.x >> 4;
  int lbase = (blockIdx.x & 15) << 8;
  const float4* rmb = (const float4*)(rm + (size_t)b * (DK_ * 128));
  float4* s4 = (float4*)srm;
  for (int idx = threadIdx.x; idx < DK_ * 128 / 4; idx += 256) s4[idx] = rmb[idx];
  __syncthreads();
  if (threadIdx.x < 128) {
    int rn = threadIdx.x;
    double ss = 0.0;
    #pragma unroll
    for (int d = 0; d < DK_; ++d) { double v = (double)srm[d * 128 + rn]; ss += v * v; }
    sinv[rn] = 1.0 / sqrt(ss);
  }
  __syncthreads();
  int l = lbase + threadIdx.x;
  const float* qrow = query + ((size_t)b * L_ + l) * DK_;
  double qd[DK_];
  #pragma unroll
  for (int d4 = 0; d4 < DK_ / 4; ++d4) {
    float4 v = ((const float4*)qrow)[d4];
    qd[4 * d4 + 0] = v.x; qd[4 * d4 + 1] = v.y;
    qd[4 * d4 + 2] = v.z; qd[4 * d4 + 3] = v.w;
  }
  int res[R_];
  #pragma unroll
  for (int r = 0; r < R_; ++r) {
    double bp = -1e300, bn = -1e300;
    int ip = 0, inn = 0;
    for (int n = 0; n < 32; ++n) {
      int rn = r * 32 + n;
      double acc = 0.0;
      #pragma unroll
      for (int d = 0; d < DK_; ++d) acc += qd[d] * (double)srm[d * 128 + rn];
      double v = acc * sinv[rn];
      if (v > bp) { bp = v; ip = n; }     // first-wins over +mm
      if (-v > bn) { bn = -v; inn = n; }  // first-wins over -mm
    }
    res[r] = (bn > bp) ? (inn + 32) : ip; // +mm indices come first on tie
  }
  ((int4*)bucket)[(size_t)b * L_ + l] = make_int4(res[0], res[1], res[2], res[3]);
}

// ---------------- Kernel 2: stable counting sort per (b, r) -----------------
__global__ __launch_bounds__(64) void sort_kernel(
    const int* __restrict__ bucket, int* __restrict__ sorted_pos,
    int* __restrict__ cchunk) {
  int b = blockIdx.x >> 2;
  int r = blockIdx.x & 3;
  __shared__ int sb[L_];
  __shared__ int hist[NB_];
  int lane = threadIdx.x;  // 64 threads, lane == bin id
  for (int p = lane; p < L_; p += 64) sb[p] = bucket[((size_t)b * L_ + p) * 4 + r];
  hist[lane] = 0;
  __syncthreads();
  for (int p = lane; p < L_; p += 64) atomicAdd(&hist[sb[p]], 1);
  __syncthreads();
  int off = 0;
  for (int u = 0; u < lane; ++u) off += hist[u];
  int* sp = sorted_pos + ((size_t)b * R_ + r) * L_;
  for (int p = 0; p < L_; ++p) {
    if (sb[p] == lane) {
      sp[off] = p;
      cchunk[((size_t)b * L_ + p) * 4 + r] = off >> 6;
      off++;
    }
  }
}

// ---------------- Kernel 3: per-chunk attention ------------------------------
__global__ __launch_bounds__(256) void attn_kernel(
    const float* __restrict__ query, const float* __restrict__ value,
    const int* __restrict__ sorted_pos, const int* __restrict__ bucket,
    const int* __restrict__ cchunk,
    float* __restrict__ att, float* __restrict__ lse_s) {
  int n = blockIdx.x & 63;
  int r = (blockIdx.x >> 6) & 3;
  int b = blockIdx.x >> 8;

  __shared__ float buf[128 * KSTR];   // K rows, later reused for V rows
  __shared__ int skpos[128];
  __shared__ int sbk[128];
  __shared__ float skinv[128];
  __shared__ int4 sck[128];

  int t = threadIdx.x;
  const int* sp = sorted_pos + ((size_t)b * R_ + r) * L_;

  if (t < 128) {
    int chunk = (t < 64) ? ((n + 63) & 63) : n;
    int pos = sp[chunk * 64 + (t & 63)];
    skpos[t] = pos;
    sbk[t] = bucket[((size_t)b * L_ + pos) * 4 + r];
    sck[t] = ((const int4*)cchunk)[(size_t)b * L_ + pos];
  }
  __syncthreads();

  // stage K (raw query rows at key positions)
  {
    int j = t >> 1, half = t & 1;
    const float* qr = query + ((size_t)b * L_ + skpos[j]) * DK_;
    #pragma unroll
    for (int u = 0; u < 8; ++u) {
      int d = half * 32 + u * 4;
      *(float4*)(buf + j * KSTR + d) = *(const float4*)(qr + d);
    }
  }
  __syncthreads();
  if (t < 128) {
    float ss = 0.f;
    #pragma unroll
    for (int d = 0; d < DK_; ++d) { float x = buf[t * KSTR + d]; ss += x * x; }
    skinv[t] = 1.0f / fmaxf(sqrtf(ss), 1e-12f);
  }
  __syncthreads();

  int i = t >> 2, jg = t & 3;       // lane = 4*i + jg within wave
  float q[DK_];
  #pragma unroll
  for (int dq = 0; dq < 16; ++dq) {
    float4 v = *(float4*)(buf + (64 + i) * KSTR + dq * 4);
    q[4 * dq] = v.x; q[4 * dq + 1] = v.y; q[4 * dq + 2] = v.z; q[4 * dq + 3] = v.w;
  }
  int qp = skpos[64 + i];
  int bq = sbk[64 + i];
  int4 cq = sck[64 + i];

  float s[32];
  #pragma unroll
  for (int jj = 0; jj < 32; ++jj) {
    int j = jj * 4 + jg;
    float acc = 0.f;
    #pragma unroll
    for (int dq = 0; dq < 16; ++dq) {
      float4 kv = *(float4*)(buf + j * KSTR + dq * 4);
      acc += q[4 * dq] * kv.x + q[4 * dq + 1] * kv.y +
             q[4 * dq + 2] * kv.z + q[4 * dq + 3] * kv.w;
    }
    float sc = acc * skinv[j] * 0.125f;
    int kp = skpos[j];
    if (qp < kp || bq != sbk[j]) sc = -1e9f;
    if (qp == kp) sc = -1e5f;
    s[jj] = sc;
  }

  // softmax over 128 keys (4 lanes per query)
  float m = -1e30f;
  #pragma unroll
  for (int jj = 0; jj < 32; ++jj) m = fmaxf(m, s[jj]);
  m = fmaxf(m, __shfl_xor(m, 1, 64));
  m = fmaxf(m, __shfl_xor(m, 2, 64));
  float sum = 0.f;
  #pragma unroll
  for (int jj = 0; jj < 32; ++jj) sum += __expf(s[jj] - m);
  sum += __shfl_xor(sum, 1, 64);
  sum += __shfl_xor(sum, 2, 64);
  float lse = m + __logf(sum);

  #pragma unroll
  for (int jj = 0; jj < 32; ++jj) {
    int j = jj * 4 + jg;
    int4 ck = sck[j];
    int cnt = (((cq.x - ck.x) & 63) <= 1) + (((cq.y - ck.y) & 63) <= 1) +
              (((cq.z - ck.z) & 63) <= 1) + (((cq.w - ck.w) & 63) <= 1);
    s[jj] = __expf(s[jj] - lse) / (float)cnt;
  }
  __syncthreads();   // everyone done reading K

  // stage V into the same buffer
  {
    int j = t >> 1, half = t & 1;
    const float* vr = value + ((size_t)b * L_ + skpos[j]) * DK_;
    #pragma unroll
    for (int u = 0; u < 8; ++u) {
      int d = half * 32 + u * 4;
      *(float4*)(buf + j * KSTR + d) = *(const float4*)(vr + d);
    }
  }
  __syncthreads();

  float acc[DK_];
  #pragma unroll
  for (int d = 0; d < DK_; ++d) acc[d] = 0.f;
  #pragma unroll
  for (int jj = 0; jj < 32; ++jj) {
    int j = jj * 4 + jg;
    float p = s[jj];
    #pragma unroll
    for (int dq = 0; dq < 16; ++dq) {
      float4 v = *(float4*)(buf + j * KSTR + dq * 4);
      acc[4 * dq] += p * v.x; acc[4 * dq + 1] += p * v.y;
      acc[4 * dq + 2] += p * v.z; acc[4 * dq + 3] += p * v.w;
    }
  }
  #pragma unroll
  for (int d = 0; d < DK_; ++d) {
    acc[d] += __shfl_xor(acc[d], 1, 64);
    acc[d] += __shfl_xor(acc[d], 2, 64);
  }
  float* arow = att + (((size_t)b * R_ + r) * L_ + qp) * DK_;
  #pragma unroll
  for (int u = 0; u < 4; ++u) {
    int d = jg * 16 + u * 4;
    *(float4*)(arow + d) = make_float4(acc[d], acc[d + 1], acc[d + 2], acc[d + 3]);
  }
  if (jg == 0) lse_s[((size_t)b * R_ + r) * L_ + qp] = lse;
}

// ---------------- Kernel 4: softmax reduction over L of lse ------------------
__global__ __launch_bounds__(256) void lsered_kernel(
    const float* __restrict__ lse_s, float* __restrict__ wred) {
  int br = blockIdx.x;
  const float* row = lse_s + (size_t)br * L_;
  __shared__ float red[4];
  int t = threadIdx.x;
  float m = -1e30f;
  for (int p = t; p < L_; p += 256) m = fmaxf(m, row[p]);
  #pragma unroll
  for (int mask = 1; mask < 64; mask <<= 1) m = fmaxf(m, __shfl_xor(m, mask, 64));
  if ((t & 63) == 0) red[t >> 6] = m;
  __syncthreads();
  m = fmaxf(fmaxf(red[0], red[1]), fmaxf(red[2], red[3]));
  __syncthreads();
  float sum = 0.f;
  for (int p = t; p < L_; p += 256) sum += __expf(row[p] - m);
  #pragma unroll
  for (int mask = 1; mask < 64; mask <<= 1) sum += __shfl_xor(sum, mask, 64);
  if ((t & 63) == 0) red[t >> 6] = sum;
  __syncthreads();
  if (t == 0) {
    wred[br * 2] = m;
    wred[br * 2 + 1] = red[0] + red[1] + red[2] + red[3];
  }
}

// ---------------- Kernel 5: weighted combine over rounds ---------------------
__global__ __launch_bounds__(256) void combine_kernel(
    const float* __restrict__ att, const float* __restrict__ lse_s,
    const float* __restrict__ wred, float* __restrict__ out) {
  size_t idx = (size_t)blockIdx.x * 256 + threadIdx.x;  // float4 index
  int d4 = idx & 15;
  int l = (idx >> 4) & (L_ - 1);
  int b = (int)(idx >> 16);
  float4 o = make_float4(0.f, 0.f, 0.f, 0.f);
  #pragma unroll
  for (int r = 0; r < R_; ++r) {
    float m = wred[(b * R_ + r) * 2];
    float sinv = 1.0f / wred[(b * R_ + r) * 2 + 1];
    float w = __expf(lse_s[((size_t)b * R_ + r) * L_ + l] - m) * sinv;
    float4 a = ((const float4*)att)[(((size_t)b * R_ + r) * L_ + l) * 16 + d4];
    o.x += w * a.x; o.y += w * a.y; o.z += w * a.z; o.w += w * a.w;
  }
  ((float4*)out)[idx] = o;
}

extern "C" void kernel_launch(void* const* d_in, const int* in_sizes, int n_in,
                              void* d_out, int out_size, void* d_ws, size_t ws_size,
                              hipStream_t stream) {
  const float* query = (const float*)d_in[0];
  const float* value = (const float*)d_in[1];
  const float* rm    = (const float*)d_in[2];
  (void)in_sizes; (void)n_in; (void)out_size; (void)ws_size;

  char* ws = (char*)d_ws;
  const size_t ATT_BYTES = (size_t)B_ * R_ * L_ * DK_ * 4;  // 64 MiB
  const size_t MB = 1048576;
  float* att        = (float*)ws;
  int*   bucket     = (int*)(ws + ATT_BYTES);
  int*   sorted_pos = (int*)(ws + ATT_BYTES + 1 * MB);
  int*   cchunk     = (int*)(ws + ATT_BYTES + 2 * MB);
  float* lse_s      = (float*)(ws + ATT_BYTES + 3 * MB);
  float* wred       = (float*)(ws + ATT_BYTES + 4 * MB);
  float* out        = (float*)d_out;

  hash_kernel<<<256, 256, 0, stream>>>(query, rm, bucket);
  sort_kernel<<<B_ * R_, 64, 0, stream>>>(bucket, sorted_pos, cchunk);
  attn_kernel<<<B_ * R_ * NB_, 256, 0, stream>>>(query, value, sorted_pos, bucket,
                                                 cchunk, att, lse_s);
  lsered_kernel<<<B_ * R_, 256, 0, stream>>>(lse_s, wred);
  combine_kernel<<<(B_ * L_ * 16) / 256, 256, 0, stream>>>(att, lse_s, wred, out);
}

// Round 2
// 362.239 us; speedup vs baseline: 2.0375x; 2.0375x over previous
//
#include <hip/hip_runtime.h>

#define B_ 16
#define L_ 4096
#define DK_ 64
#define R_ 4
#define NB_ 64
#define BL_ 64

typedef __attribute__((ext_vector_type(8))) short bf16x8;
typedef __attribute__((ext_vector_type(4))) float f32x4;

__device__ __forceinline__ unsigned short f2bf(float f) {
  unsigned u = __float_as_uint(f);
  return (unsigned short)((u + 0x7FFFu + ((u >> 16) & 1u)) >> 16);
}
__device__ __forceinline__ int swz(int row) { return (row & 7) ^ ((row >> 3) & 7); }

// ---------------- Kernel 1: LSH hashing (fp64 dots, KEPT BYTE-IDENTICAL) ----
__global__ __launch_bounds__(256) void hash_kernel(
    const float* __restrict__ query, const float* __restrict__ rm,
    int* __restrict__ bucket) {
  __shared__ float srm[DK_ * 128];   // [d][rn], rn = r*32+n
  __shared__ double sinv[128];
  int b = blockIdx.x >> 4;
  int lbase = (blockIdx.x & 15) << 8;
  const float4* rmb = (const float4*)(rm + (size_t)b * (DK_ * 128));
  float4* s4 = (float4*)srm;
  for (int idx = threadIdx.x; idx < DK_ * 128 / 4; idx += 256) s4[idx] = rmb[idx];
  __syncthreads();
  if (threadIdx.x < 128) {
    int rn = threadIdx.x;
    double ss = 0.0;
    #pragma unroll
    for (int d = 0; d < DK_; ++d) { double v = (double)srm[d * 128 + rn]; ss += v * v; }
    sinv[rn] = 1.0 / sqrt(ss);
  }
  __syncthreads();
  int l = lbase + threadIdx.x;
  const float* qrow = query + ((size_t)b * L_ + l) * DK_;
  double qd[DK_];
  #pragma unroll
  for (int d4 = 0; d4 < DK_ / 4; ++d4) {
    float4 v = ((const float4*)qrow)[d4];
    qd[4 * d4 + 0] = v.x; qd[4 * d4 + 1] = v.y;
    qd[4 * d4 + 2] = v.z; qd[4 * d4 + 3] = v.w;
  }
  int res[R_];
  #pragma unroll
  for (int r = 0; r < R_; ++r) {
    double bp = -1e300, bn = -1e300;
    int ip = 0, inn = 0;
    for (int n = 0; n < 32; ++n) {
      int rn = r * 32 + n;
      double acc = 0.0;
      #pragma unroll
      for (int d = 0; d < DK_; ++d) acc += qd[d] * (double)srm[d * 128 + rn];
      double v = acc * sinv[rn];
      if (v > bp) { bp = v; ip = n; }     // first-wins over +mm
      if (-v > bn) { bn = -v; inn = n; }  // first-wins over -mm
    }
    res[r] = (bn > bp) ? (inn + 32) : ip; // +mm indices come first on tie
  }
  ((int4*)bucket)[(size_t)b * L_ + l] = make_int4(res[0], res[1], res[2], res[3]);
}

// ---------------- Kernel 2: single-wave ballot counting sort per (b, r) -----
__global__ __launch_bounds__(64) void sort_kernel(
    const int* __restrict__ bucket, int* __restrict__ sorted_pos,
    unsigned char* __restrict__ cpack) {
  int b = blockIdx.x >> 2;
  int r = blockIdx.x & 3;
  __shared__ int off[NB_];
  int lane = threadIdx.x;
  const int* bb = bucket + (size_t)b * L_ * 4 + r;
  unsigned long long ltmask = (1ull << lane) - 1ull;

  int binv[64];
  #pragma unroll
  for (int g = 0; g < 64; ++g) binv[g] = bb[(g * 64 + lane) * 4];

  off[lane] = 0;
  __syncthreads();
  // pass 1: histogram via ballot match-masks (leaders accumulate)
  #pragma unroll
  for (int g = 0; g < 64; ++g) {
    int bin = binv[g];
    unsigned long long m = ~0ull;
    #pragma unroll
    for (int k = 0; k < 6; ++k) {
      unsigned long long bal = __ballot((bin >> k) & 1);
      m &= ((bin >> k) & 1) ? bal : ~bal;
    }
    if ((m & ltmask) == 0ull) off[bin] = off[bin] + __popcll(m);
  }
  __syncthreads();
  // exclusive prefix over 64 bins
  int pre = 0;
  for (int u = 0; u < 64; ++u) { int h = off[u]; pre += (u < lane) ? h : 0; }
  __syncthreads();
  off[lane] = pre;
  __syncthreads();
  // pass 2: stable scatter
  int* sp = sorted_pos + ((size_t)b * R_ + r) * L_;
  unsigned char* cp = cpack + (size_t)b * L_ * 4 + r;
  #pragma unroll
  for (int g = 0; g < 64; ++g) {
    int p = g * 64 + lane;
    int bin = binv[g];
    unsigned long long m = ~0ull;
    #pragma unroll
    for (int k = 0; k < 6; ++k) {
      unsigned long long bal = __ballot((bin >> k) & 1);
      m &= ((bin >> k) & 1) ? bal : ~bal;
    }
    int rank = (int)__popcll(m & ltmask);
    int base = off[bin];
    int slot = base + rank;
    sp[slot] = p;
    cp[(size_t)p * 4] = (unsigned char)(slot >> 6);
    if (rank == 0) off[bin] = base + (int)__popcll(m);
  }
}

// ---------------- Kernel 3: per-chunk attention (bf16 MFMA) ------------------
__global__ __launch_bounds__(256) void attn_kernel(
    const float* __restrict__ query, const float* __restrict__ value,
    const int* __restrict__ sorted_pos, const int* __restrict__ bucket,
    const int* __restrict__ cpack,
    float* __restrict__ att, float* __restrict__ lse_s) {
  int wg = (int)blockIdx.x;
  wg = (wg & 7) * (B_ * R_ * NB_ / 8) + (wg >> 3);   // XCD-contiguous swizzle
  int n = wg & 63;
  int r = (wg >> 6) & 3;
  int b = wg >> 8;

  __shared__ __align__(16) short bufK[128 * 64];   // K bf16; reused as VT[64][128]
  __shared__ __align__(16) short bufQ[64 * 64];    // Q*0.125 bf16
  __shared__ __align__(16) short bufP[64 * 128];   // P bf16
  __shared__ int skpos[128];
  __shared__ int sbk[128];
  __shared__ int sckp[128];

  int t = threadIdx.x;
  const int* sp = sorted_pos + ((size_t)b * R_ + r) * L_;

  if (t < 128) {
    int chunk = (t < 64) ? ((n + 63) & 63) : n;
    int pos = sp[chunk * 64 + (t & 63)];
    skpos[t] = pos;
    sbk[t] = bucket[((size_t)b * L_ + pos) * 4 + r];
    sckp[t] = ((const int*)cpack)[(size_t)b * L_ + pos];
  }
  __syncthreads();

  // ---- stage K (normalized bf16) and Q (raw*0.125 bf16) ----
  {
    int j = t >> 1, half = t & 1;
    const float* qr = query + ((size_t)b * L_ + skpos[j]) * DK_ + half * 32;
    float v[32];
    float ss = 0.f;
    #pragma unroll
    for (int u = 0; u < 8; ++u) {
      float4 x = ((const float4*)qr)[u];
      v[u*4+0] = x.x; v[u*4+1] = x.y; v[u*4+2] = x.z; v[u*4+3] = x.w;
      ss += x.x*x.x + x.y*x.y + x.z*x.z + x.w*x.w;
    }
    ss += __shfl_xor(ss, 1);
    float inv = 1.0f / fmaxf(sqrtf(ss), 1e-12f);
    short* krow = bufK + j * 64;
    #pragma unroll
    for (int u = 0; u < 4; ++u) {
      int d0 = half * 32 + u * 8;
      bf16x8 pk;
      #pragma unroll
      for (int e = 0; e < 8; ++e) pk[e] = (short)f2bf(v[u*8+e] * inv);
      *(bf16x8*)(krow + (((d0 >> 3) ^ swz(j)) << 3)) = pk;
    }
    if (j >= 64) {
      int jq = j - 64;
      short* qrp = bufQ + jq * 64;
      #pragma unroll
      for (int u = 0; u < 4; ++u) {
        int d0 = half * 32 + u * 8;
        bf16x8 pk;
        #pragma unroll
        for (int e = 0; e < 8; ++e) pk[e] = (short)f2bf(v[u*8+e] * 0.125f);
        *(bf16x8*)(qrp + (((d0 >> 3) ^ swz(jq)) << 3)) = pk;
      }
    }
  }
  __syncthreads();

  int l = t & 63, w = t >> 6;
  // ---- QK^T via MFMA: wave w owns query rows 16w..16w+15 ----
  f32x4 acc[8];
  #pragma unroll
  for (int tt = 0; tt < 8; ++tt) acc[tt] = (f32x4){0.f, 0.f, 0.f, 0.f};
  {
    int qrow = w * 16 + (l & 15);
    const short* qp_ = bufQ + qrow * 64;
    bf16x8 a0 = *(const bf16x8*)(qp_ + ((((l >> 4)) ^ swz(qrow)) << 3));
    bf16x8 a1 = *(const bf16x8*)(qp_ + (((4 + (l >> 4)) ^ swz(qrow)) << 3));
    #pragma unroll
    for (int tt = 0; tt < 8; ++tt) {
      int krow = tt * 16 + (l & 15);
      const short* kp_ = bufK + krow * 64;
      bf16x8 b0 = *(const bf16x8*)(kp_ + ((((l >> 4)) ^ swz(krow)) << 3));
      bf16x8 b1 = *(const bf16x8*)(kp_ + (((4 + (l >> 4)) ^ swz(krow)) << 3));
      acc[tt] = __builtin_amdgcn_mfma_f32_16x16x32_bf16(a0, b0, acc[tt], 0, 0, 0);
      acc[tt] = __builtin_amdgcn_mfma_f32_16x16x32_bf16(a1, b1, acc[tt], 0, 0, 0);
    }
  }
  __syncthreads();   // all waves done reading bufK/bufQ

  // ---- issue V loads early (latency hides under softmax VALU) ----
  int pi = t >> 2, qd = t & 3;
  const float* vr0 = value + ((size_t)b * L_ + skpos[2 * pi]) * DK_ + qd * 16;
  const float* vr1 = value + ((size_t)b * L_ + skpos[2 * pi + 1]) * DK_ + qd * 16;
  float4 va[4], vb4[4];
  #pragma unroll
  for (int c4 = 0; c4 < 4; ++c4) { va[c4] = ((const float4*)vr0)[c4]; vb4[c4] = ((const float4*)vr1)[c4]; }

  // ---- masks + softmax, all in registers on the MFMA D-layout ----
  int kp[8], bk[8], ck[8];
  #pragma unroll
  for (int tt = 0; tt < 8; ++tt) {
    int col = tt * 16 + (l & 15);
    kp[tt] = skpos[col]; bk[tt] = sbk[col]; ck[tt] = sckp[col];
  }
  float st[8][4];
  float lse[4], psum[4];
  int qprow[4];
  #pragma unroll
  for (int j = 0; j < 4; ++j) {
    int qrow = w * 16 + (l >> 4) * 4 + j;
    int qp2 = skpos[64 + qrow];
    int bq = sbk[64 + qrow];
    qprow[j] = qp2;
    #pragma unroll
    for (int tt = 0; tt < 8; ++tt) {
      float s = acc[tt][j];
      s = ((qp2 < kp[tt]) || (bq != bk[tt])) ? -1e9f : s;
      s = (qp2 == kp[tt]) ? -1e5f : s;
      st[tt][j] = s;
    }
    float m = st[0][j];
    #pragma unroll
    for (int tt = 1; tt < 8; ++tt) m = fmaxf(m, st[tt][j]);
    m = fmaxf(m, __shfl_xor(m, 1));
    m = fmaxf(m, __shfl_xor(m, 2));
    m = fmaxf(m, __shfl_xor(m, 4));
    m = fmaxf(m, __shfl_xor(m, 8));
    float sum = 0.f;
    #pragma unroll
    for (int tt = 0; tt < 8; ++tt) { float e = __expf(st[tt][j] - m); st[tt][j] = e; sum += e; }
    sum += __shfl_xor(sum, 1);
    sum += __shfl_xor(sum, 2);
    sum += __shfl_xor(sum, 4);
    sum += __shfl_xor(sum, 8);
    psum[j] = sum;
    lse[j] = m + __logf(sum);
  }

  // ---- dup-count (SWAR) + P -> LDS (bf16) ----
  #pragma unroll
  for (int j = 0; j < 4; ++j) {
    int qrow = w * 16 + (l >> 4) * 4 + j;
    unsigned aq = (unsigned)sckp[64 + qrow] | 0x40404040u;
    float isum = 1.0f / psum[j];
    #pragma unroll
    for (int tt = 0; tt < 8; ++tt) {
      unsigned e = (aq - (unsigned)ck[tt]) & 0x3E3E3E3Eu;
      unsigned y = (e - 0x01010101u) & ~e & 0x80808080u;
      int cnt = __popc(y);
      float invc = (cnt == 1) ? 1.f : (cnt == 2) ? 0.5f : (cnt == 3) ? (1.f / 3.f) : 0.25f;
      float p = st[tt][j] * isum * invc;
      int col = tt * 16 + (l & 15);
      bufP[qrow * 128 + (((col >> 3) ^ swz(qrow)) << 3) + (col & 7)] = (short)f2bf(p);
    }
  }
  if ((l & 15) == 0) {
    #pragma unroll
    for (int j = 0; j < 4; ++j)
      lse_s[((size_t)b * R_ + r) * L_ + qprow[j]] = lse[j];
  }

  // ---- VT staging into freed bufK: VT[n][k] packed pairs along k ----
  short* VT = bufK;
  #pragma unroll
  for (int c4 = 0; c4 < 4; ++c4) {
    float4 x0 = va[c4], x1 = vb4[c4];
    #pragma unroll
    for (int cc = 0; cc < 4; ++cc) {
      float f0 = (cc == 0) ? x0.x : (cc == 1) ? x0.y : (cc == 2) ? x0.z : x0.w;
      float f1 = (cc == 0) ? x1.x : (cc == 1) ? x1.y : (cc == 2) ? x1.z : x1.w;
      unsigned pk2 = (unsigned)f2bf(f0) | ((unsigned)f2bf(f1) << 16);
      int nrow = qd * 16 + c4 * 4 + cc;
      int k0 = 2 * pi;
      int a = nrow * 128 + (((k0 >> 3) ^ swz(nrow)) << 3) + (k0 & 7);
      *(unsigned*)(VT + a) = pk2;
    }
  }
  __syncthreads();

  // ---- PV via MFMA ----
  f32x4 o[4];
  #pragma unroll
  for (int nt = 0; nt < 4; ++nt) o[nt] = (f32x4){0.f, 0.f, 0.f, 0.f};
  {
    int qrow = w * 16 + (l & 15);
    #pragma unroll
    for (int ks = 0; ks < 4; ++ks) {
      bf16x8 pa = *(const bf16x8*)(bufP + qrow * 128 + (((ks * 4 + (l >> 4)) ^ swz(qrow)) << 3));
      #pragma unroll
      for (int nt = 0; nt < 4; ++nt) {
        int vrow = nt * 16 + (l & 15);
        bf16x8 vb = *(const bf16x8*)(VT + vrow * 128 + (((ks * 4 + (l >> 4)) ^ swz(vrow)) << 3));
        o[nt] = __builtin_amdgcn_mfma_f32_16x16x32_bf16(pa, vb, o[nt], 0, 0, 0);
      }
    }
  }

  // ---- scatter att rows (fp32) ----
  #pragma unroll
  for (int jj = 0; jj < 4; ++jj) {
    float* arow = att + (((size_t)b * R_ + r) * L_ + qprow[jj]) * DK_;
    #pragma unroll
    for (int nt = 0; nt < 4; ++nt) arow[nt * 16 + (l & 15)] = o[nt][jj];
  }
}

// ---------------- Kernel 4: softmax reduction over L of lse ------------------
__global__ __launch_bounds__(256) void lsered_kernel(
    const float* __restrict__ lse_s, float* __restrict__ wred) {
  int br = blockIdx.x;
  const float* row = lse_s + (size_t)br * L_;
  __shared__ float red[4];
  int t = threadIdx.x;
  float m = -1e30f;
  for (int p = t; p < L_; p += 256) m = fmaxf(m, row[p]);
  #pragma unroll
  for (int mask = 1; mask < 64; mask <<= 1) m = fmaxf(m, __shfl_xor(m, mask, 64));
  if ((t & 63) == 0) red[t >> 6] = m;
  __syncthreads();
  m = fmaxf(fmaxf(red[0], red[1]), fmaxf(red[2], red[3]));
  __syncthreads();
  float sum = 0.f;
  for (int p = t; p < L_; p += 256) sum += __expf(row[p] - m);
  #pragma unroll
  for (int mask = 1; mask < 64; mask <<= 1) sum += __shfl_xor(sum, mask, 64);
  if ((t & 63) == 0) red[t >> 6] = sum;
  __syncthreads();
  if (t == 0) {
    wred[br * 2] = m;
    wred[br * 2 + 1] = red[0] + red[1] + red[2] + red[3];
  }
}

// ---------------- Kernel 5: weighted combine over rounds ---------------------
__global__ __launch_bounds__(256) void combine_kernel(
    const float* __restrict__ att, const float* __restrict__ lse_s,
    const float* __restrict__ wred, float* __restrict__ out) {
  size_t idx = (size_t)blockIdx.x * 256 + threadIdx.x;  // float4 index
  int d4 = idx & 15;
  int l = (idx >> 4) & (L_ - 1);
  int b = (int)(idx >> 16);
  float4 o = make_float4(0.f, 0.f, 0.f, 0.f);
  #pragma unroll
  for (int r = 0; r < R_; ++r) {
    float m = wred[(b * R_ + r) * 2];
    float sinv = 1.0f / wred[(b * R_ + r) * 2 + 1];
    float w = __expf(lse_s[((size_t)b * R_ + r) * L_ + l] - m) * sinv;
    float4 a = ((const float4*)att)[(((size_t)b * R_ + r) * L_ + l) * 16 + d4];
    o.x += w * a.x; o.y += w * a.y; o.z += w * a.z; o.w += w * a.w;
  }
  ((float4*)out)[idx] = o;
}

extern "C" void kernel_launch(void* const* d_in, const int* in_sizes, int n_in,
                              void* d_out, int out_size, void* d_ws, size_t ws_size,
                              hipStream_t stream) {
  const float* query = (const float*)d_in[0];
  const float* value = (const float*)d_in[1];
  const float* rm    = (const float*)d_in[2];
  (void)in_sizes; (void)n_in; (void)out_size; (void)ws_size;

  char* ws = (char*)d_ws;
  const size_t ATT_BYTES = (size_t)B_ * R_ * L_ * DK_ * 4;  // 64 MiB
  const size_t MB = 1048576;
  float*         att        = (float*)ws;
  int*           bucket     = (int*)(ws + ATT_BYTES);
  int*           sorted_pos = (int*)(ws + ATT_BYTES + 1 * MB);
  unsigned char* cpack      = (unsigned char*)(ws + ATT_BYTES + 2 * MB);
  float*         lse_s      = (float*)(ws + ATT_BYTES + 3 * MB);
  float*         wred       = (float*)(ws + ATT_BYTES + 4 * MB);
  float* out = (float*)d_out;

  hash_kernel<<<256, 256, 0, stream>>>(query, rm, bucket);
  sort_kernel<<<B_ * R_, 64, 0, stream>>>(bucket, sorted_pos, cpack);
  attn_kernel<<<B_ * R_ * NB_, 256, 0, stream>>>(query, value, sorted_pos, bucket,
                                                 (const int*)cpack, att, lse_s);
  lsered_kernel<<<B_ * R_, 256, 0, stream>>>(lse_s, wred);
  combine_kernel<<<(B_ * L_ * 16) / 256, 256, 0, stream>>>(att, lse_s, wred, out);
}

// Round 3
// 229.449 us; speedup vs baseline: 3.2167x; 1.5787x over previous
//
#include <hip/hip_runtime.h>

#define B_ 16
#define L_ 4096
#define DK_ 64
#define R_ 4
#define NB_ 64
#define BL_ 64

typedef __attribute__((ext_vector_type(8))) short bf16x8;
typedef __attribute__((ext_vector_type(4))) float f32x4;

__device__ __forceinline__ unsigned short f2bf(float f) {
  unsigned u = __float_as_uint(f);
  return (unsigned short)((u + 0x7FFFu + ((u >> 16) & 1u)) >> 16);
}
__device__ __forceinline__ float bf2f(unsigned short u) {
  return __uint_as_float(((unsigned)u) << 16);
}
__device__ __forceinline__ int swz(int row) { return (row & 7) ^ ((row >> 3) & 7); }

// ---------------- Kernel 1: LSH hashing (fp64 dots, KEPT BYTE-IDENTICAL) ----
__global__ __launch_bounds__(256) void hash_kernel(
    const float* __restrict__ query, const float* __restrict__ rm,
    int* __restrict__ bucket) {
  __shared__ float srm[DK_ * 128];   // [d][rn], rn = r*32+n
  __shared__ double sinv[128];
  int b = blockIdx.x >> 4;
  int lbase = (blockIdx.x & 15) << 8;
  const float4* rmb = (const float4*)(rm + (size_t)b * (DK_ * 128));
  float4* s4 = (float4*)srm;
  for (int idx = threadIdx.x; idx < DK_ * 128 / 4; idx += 256) s4[idx] = rmb[idx];
  __syncthreads();
  if (threadIdx.x < 128) {
    int rn = threadIdx.x;
    double ss = 0.0;
    #pragma unroll
    for (int d = 0; d < DK_; ++d) { double v = (double)srm[d * 128 + rn]; ss += v * v; }
    sinv[rn] = 1.0 / sqrt(ss);
  }
  __syncthreads();
  int l = lbase + threadIdx.x;
  const float* qrow = query + ((size_t)b * L_ + l) * DK_;
  double qd[DK_];
  #pragma unroll
  for (int d4 = 0; d4 < DK_ / 4; ++d4) {
    float4 v = ((const float4*)qrow)[d4];
    qd[4 * d4 + 0] = v.x; qd[4 * d4 + 1] = v.y;
    qd[4 * d4 + 2] = v.z; qd[4 * d4 + 3] = v.w;
  }
  int res[R_];
  #pragma unroll
  for (int r = 0; r < R_; ++r) {
    double bp = -1e300, bn = -1e300;
    int ip = 0, inn = 0;
    for (int n = 0; n < 32; ++n) {
      int rn = r * 32 + n;
      double acc = 0.0;
      #pragma unroll
      for (int d = 0; d < DK_; ++d) acc += qd[d] * (double)srm[d * 128 + rn];
      double v = acc * sinv[rn];
      if (v > bp) { bp = v; ip = n; }     // first-wins over +mm
      if (-v > bn) { bn = -v; inn = n; }  // first-wins over -mm
    }
    res[r] = (bn > bp) ? (inn + 32) : ip; // +mm indices come first on tie
  }
  ((int4*)bucket)[(size_t)b * L_ + l] = make_int4(res[0], res[1], res[2], res[3]);
}

// ------- Kernel 2: 16-wave two-level stable counting sort per (b, r) --------
__global__ __launch_bounds__(1024) void sort_kernel(
    const int* __restrict__ bucket, int* __restrict__ sorted_pos,
    unsigned char* __restrict__ cpack) {
  int b = blockIdx.x >> 2;
  int r = blockIdx.x & 3;
  __shared__ int hist[64 * 65];   // [chunk][bin], stride 65
  __shared__ int off[64];
  int t = threadIdx.x, lane = t & 63, w = t >> 6;
  unsigned long long ltmask = (1ull << lane) - 1ull;
  const int* bb = bucket + (size_t)b * L_ * 4 + r;

  int binv[4], rank[4];
  #pragma unroll
  for (int u = 0; u < 4; ++u)
    binv[u] = bb[(size_t)((w * 4 + u) * 64 + lane) * 4];

  for (int idx = t; idx < 64 * 65; idx += 1024) hist[idx] = 0;
  __syncthreads();

  // pass 1: per-chunk histogram via ballot match-masks; save ranks
  #pragma unroll
  for (int u = 0; u < 4; ++u) {
    int bin = binv[u];
    unsigned long long m = ~0ull;
    #pragma unroll
    for (int k = 0; k < 6; ++k) {
      unsigned long long bal = __ballot((bin >> k) & 1);
      m &= ((bin >> k) & 1) ? bal : ~bal;
    }
    rank[u] = (int)__popcll(m & ltmask);
    if (rank[u] == 0) hist[(w * 4 + u) * 65 + bin] = (int)__popcll(m);
  }
  __syncthreads();

  // pass 2 (wave 0): per-bin exclusive prefix over chunks + bin-offset scan
  if (w == 0) {
    int run = 0;
    for (int g = 0; g < 64; ++g) {
      int v = hist[g * 65 + lane];
      hist[g * 65 + lane] = run;
      run += v;
    }
    int inc = run;
    #pragma unroll
    for (int d = 1; d < 64; d <<= 1) {
      int y = __shfl_up(inc, d, 64);
      if (lane >= d) inc += y;
    }
    off[lane] = inc - run;
  }
  __syncthreads();

  // pass 3: stable scatter
  int* sp = sorted_pos + ((size_t)b * R_ + r) * L_;
  unsigned char* cp = cpack + (size_t)b * L_ * 4 + r;
  #pragma unroll
  for (int u = 0; u < 4; ++u) {
    int g = w * 4 + u;
    int bin = binv[u];
    int slot = off[bin] + hist[g * 65 + bin] + rank[u];
    sp[slot] = g * 64 + lane;
    cp[(size_t)(g * 64 + lane) * 4] = (unsigned char)(slot >> 6);
  }
}

// ---------------- Kernel 3: per-chunk attention (bf16 MFMA) ------------------
__global__ __launch_bounds__(256) void attn_kernel(
    const float* __restrict__ query, const float* __restrict__ value,
    const int* __restrict__ sorted_pos, const int* __restrict__ bucket,
    const int* __restrict__ cpack,
    unsigned short* __restrict__ att, float* __restrict__ lse_s) {
  int wg = (int)blockIdx.x;
  wg = (wg & 7) * (B_ * R_ * NB_ / 8) + (wg >> 3);   // XCD-contiguous swizzle
  int n = wg & 63;
  int r = (wg >> 6) & 3;
  int b = wg >> 8;

  __shared__ __align__(16) short bufK[128 * 64];   // K bf16; reused as VT[64][128]
  __shared__ __align__(16) short bufQ[64 * 64];    // Q*0.125 bf16
  __shared__ __align__(16) short bufP[64 * 128];   // P bf16
  __shared__ int skpos[128];
  __shared__ int sbk[128];
  __shared__ int sckp[128];

  int t = threadIdx.x;
  const int* sp = sorted_pos + ((size_t)b * R_ + r) * L_;

  if (t < 128) {
    int chunk = (t < 64) ? ((n + 63) & 63) : n;
    int pos = sp[chunk * 64 + (t & 63)];
    skpos[t] = pos;
    sbk[t] = bucket[((size_t)b * L_ + pos) * 4 + r];
    sckp[t] = ((const int*)cpack)[(size_t)b * L_ + pos];
  }
  __syncthreads();

  // ---- stage K (normalized bf16) and Q (raw*0.125 bf16) ----
  {
    int j = t >> 1, half = t & 1;
    const float* qr = query + ((size_t)b * L_ + skpos[j]) * DK_ + half * 32;
    float v[32];
    float ss = 0.f;
    #pragma unroll
    for (int u = 0; u < 8; ++u) {
      float4 x = ((const float4*)qr)[u];
      v[u*4+0] = x.x; v[u*4+1] = x.y; v[u*4+2] = x.z; v[u*4+3] = x.w;
      ss += x.x*x.x + x.y*x.y + x.z*x.z + x.w*x.w;
    }
    ss += __shfl_xor(ss, 1);
    float inv = 1.0f / fmaxf(sqrtf(ss), 1e-12f);
    short* krow = bufK + j * 64;
    #pragma unroll
    for (int u = 0; u < 4; ++u) {
      int d0 = half * 32 + u * 8;
      bf16x8 pk;
      #pragma unroll
      for (int e = 0; e < 8; ++e) pk[e] = (short)f2bf(v[u*8+e] * inv);
      *(bf16x8*)(krow + (((d0 >> 3) ^ swz(j)) << 3)) = pk;
    }
    if (j >= 64) {
      int jq = j - 64;
      short* qrp = bufQ + jq * 64;
      #pragma unroll
      for (int u = 0; u < 4; ++u) {
        int d0 = half * 32 + u * 8;
        bf16x8 pk;
        #pragma unroll
        for (int e = 0; e < 8; ++e) pk[e] = (short)f2bf(v[u*8+e] * 0.125f);
        *(bf16x8*)(qrp + (((d0 >> 3) ^ swz(jq)) << 3)) = pk;
      }
    }
  }
  __syncthreads();

  int l = t & 63, w = t >> 6;
  // ---- QK^T via MFMA: wave w owns query rows 16w..16w+15 ----
  f32x4 acc[8];
  #pragma unroll
  for (int tt = 0; tt < 8; ++tt) acc[tt] = (f32x4){0.f, 0.f, 0.f, 0.f};
  {
    int qrow = w * 16 + (l & 15);
    const short* qp_ = bufQ + qrow * 64;
    bf16x8 a0 = *(const bf16x8*)(qp_ + ((((l >> 4)) ^ swz(qrow)) << 3));
    bf16x8 a1 = *(const bf16x8*)(qp_ + (((4 + (l >> 4)) ^ swz(qrow)) << 3));
    #pragma unroll
    for (int tt = 0; tt < 8; ++tt) {
      int krow = tt * 16 + (l & 15);
      const short* kp_ = bufK + krow * 64;
      bf16x8 b0 = *(const bf16x8*)(kp_ + ((((l >> 4)) ^ swz(krow)) << 3));
      bf16x8 b1 = *(const bf16x8*)(kp_ + (((4 + (l >> 4)) ^ swz(krow)) << 3));
      acc[tt] = __builtin_amdgcn_mfma_f32_16x16x32_bf16(a0, b0, acc[tt], 0, 0, 0);
      acc[tt] = __builtin_amdgcn_mfma_f32_16x16x32_bf16(a1, b1, acc[tt], 0, 0, 0);
    }
  }
  __syncthreads();   // all waves done reading bufK/bufQ

  // ---- issue V loads early (latency hides under softmax VALU) ----
  int pi = t >> 2, qd = t & 3;
  const float* vr0 = value + ((size_t)b * L_ + skpos[2 * pi]) * DK_ + qd * 16;
  const float* vr1 = value + ((size_t)b * L_ + skpos[2 * pi + 1]) * DK_ + qd * 16;
  float4 va[4], vb4[4];
  #pragma unroll
  for (int c4 = 0; c4 < 4; ++c4) { va[c4] = ((const float4*)vr0)[c4]; vb4[c4] = ((const float4*)vr1)[c4]; }

  // ---- masks + softmax, all in registers on the MFMA D-layout ----
  int kp[8], bk[8], ck[8];
  #pragma unroll
  for (int tt = 0; tt < 8; ++tt) {
    int col = tt * 16 + (l & 15);
    kp[tt] = skpos[col]; bk[tt] = sbk[col]; ck[tt] = sckp[col];
  }
  float st[8][4];
  float lse[4], psum[4];
  int qprow[4];
  #pragma unroll
  for (int j = 0; j < 4; ++j) {
    int qrow = w * 16 + (l >> 4) * 4 + j;
    int qp2 = skpos[64 + qrow];
    int bq = sbk[64 + qrow];
    qprow[j] = qp2;
    #pragma unroll
    for (int tt = 0; tt < 8; ++tt) {
      float s = acc[tt][j];
      s = ((qp2 < kp[tt]) || (bq != bk[tt])) ? -1e9f : s;
      s = (qp2 == kp[tt]) ? -1e5f : s;
      st[tt][j] = s;
    }
    float m = st[0][j];
    #pragma unroll
    for (int tt = 1; tt < 8; ++tt) m = fmaxf(m, st[tt][j]);
    m = fmaxf(m, __shfl_xor(m, 1));
    m = fmaxf(m, __shfl_xor(m, 2));
    m = fmaxf(m, __shfl_xor(m, 4));
    m = fmaxf(m, __shfl_xor(m, 8));
    float sum = 0.f;
    #pragma unroll
    for (int tt = 0; tt < 8; ++tt) { float e = __expf(st[tt][j] - m); st[tt][j] = e; sum += e; }
    sum += __shfl_xor(sum, 1);
    sum += __shfl_xor(sum, 2);
    sum += __shfl_xor(sum, 4);
    sum += __shfl_xor(sum, 8);
    psum[j] = sum;
    lse[j] = m + __logf(sum);
  }

  // ---- dup-count (SWAR) + P -> LDS (bf16) ----
  #pragma unroll
  for (int j = 0; j < 4; ++j) {
    int qrow = w * 16 + (l >> 4) * 4 + j;
    unsigned aq = (unsigned)sckp[64 + qrow] | 0x40404040u;
    float isum = 1.0f / psum[j];
    #pragma unroll
    for (int tt = 0; tt < 8; ++tt) {
      unsigned e = (aq - (unsigned)ck[tt]) & 0x3E3E3E3Eu;
      unsigned y = (e - 0x01010101u) & ~e & 0x80808080u;
      int cnt = __popc(y);
      float invc = (cnt == 1) ? 1.f : (cnt == 2) ? 0.5f : (cnt == 3) ? (1.f / 3.f) : 0.25f;
      float p = st[tt][j] * isum * invc;
      int col = tt * 16 + (l & 15);
      bufP[qrow * 128 + (((col >> 3) ^ swz(qrow)) << 3) + (col & 7)] = (short)f2bf(p);
    }
  }
  if ((l & 15) == 0) {
    #pragma unroll
    for (int j = 0; j < 4; ++j)
      lse_s[((size_t)b * R_ + r) * L_ + qprow[j]] = lse[j];
  }

  // ---- VT staging into freed bufK: VT[n][k] packed pairs along k ----
  short* VT = bufK;
  #pragma unroll
  for (int c4 = 0; c4 < 4; ++c4) {
    float4 x0 = va[c4], x1 = vb4[c4];
    #pragma unroll
    for (int cc = 0; cc < 4; ++cc) {
      float f0 = (cc == 0) ? x0.x : (cc == 1) ? x0.y : (cc == 2) ? x0.z : x0.w;
      float f1 = (cc == 0) ? x1.x : (cc == 1) ? x1.y : (cc == 2) ? x1.z : x1.w;
      unsigned pk2 = (unsigned)f2bf(f0) | ((unsigned)f2bf(f1) << 16);
      int nrow = qd * 16 + c4 * 4 + cc;
      int k0 = 2 * pi;
      int a = nrow * 128 + (((k0 >> 3) ^ swz(nrow)) << 3) + (k0 & 7);
      *(unsigned*)(VT + a) = pk2;
    }
  }
  __syncthreads();

  // ---- PV via MFMA ----
  f32x4 o[4];
  #pragma unroll
  for (int nt = 0; nt < 4; ++nt) o[nt] = (f32x4){0.f, 0.f, 0.f, 0.f};
  {
    int qrow = w * 16 + (l & 15);
    #pragma unroll
    for (int ks = 0; ks < 4; ++ks) {
      bf16x8 pa = *(const bf16x8*)(bufP + qrow * 128 + (((ks * 4 + (l >> 4)) ^ swz(qrow)) << 3));
      #pragma unroll
      for (int nt = 0; nt < 4; ++nt) {
        int vrow = nt * 16 + (l & 15);
        bf16x8 vb = *(const bf16x8*)(VT + vrow * 128 + (((ks * 4 + (l >> 4)) ^ swz(vrow)) << 3));
        o[nt] = __builtin_amdgcn_mfma_f32_16x16x32_bf16(pa, vb, o[nt], 0, 0, 0);
      }
    }
  }

  // ---- scatter att rows (bf16) ----
  #pragma unroll
  for (int jj = 0; jj < 4; ++jj) {
    unsigned short* arow = att + (((size_t)b * R_ + r) * L_ + qprow[jj]) * DK_;
    #pragma unroll
    for (int nt = 0; nt < 4; ++nt) arow[nt * 16 + (l & 15)] = f2bf(o[nt][jj]);
  }
}

// ---------------- Kernel 4: softmax reduction over L of lse ------------------
__global__ __launch_bounds__(256) void lsered_kernel(
    const float* __restrict__ lse_s, float* __restrict__ wred) {
  int br = blockIdx.x;
  const float* row = lse_s + (size_t)br * L_;
  __shared__ float red[4];
  int t = threadIdx.x;
  float m = -1e30f;
  for (int p = t; p < L_; p += 256) m = fmaxf(m, row[p]);
  #pragma unroll
  for (int mask = 1; mask < 64; mask <<= 1) m = fmaxf(m, __shfl_xor(m, mask, 64));
  if ((t & 63) == 0) red[t >> 6] = m;
  __syncthreads();
  m = fmaxf(fmaxf(red[0], red[1]), fmaxf(red[2], red[3]));
  __syncthreads();
  float sum = 0.f;
  for (int p = t; p < L_; p += 256) sum += __expf(row[p] - m);
  #pragma unroll
  for (int mask = 1; mask < 64; mask <<= 1) sum += __shfl_xor(sum, mask, 64);
  if ((t & 63) == 0) red[t >> 6] = sum;
  __syncthreads();
  if (t == 0) {
    wred[br * 2] = m;
    wred[br * 2 + 1] = red[0] + red[1] + red[2] + red[3];
  }
}

// ---------------- Kernel 5: weighted combine over rounds ---------------------
__global__ __launch_bounds__(256) void combine_kernel(
    const unsigned short* __restrict__ att, const float* __restrict__ lse_s,
    const float* __restrict__ wred, float* __restrict__ out) {
  size_t idx = (size_t)blockIdx.x * 256 + threadIdx.x;  // float4 index
  int d4 = idx & 15;
  int l = (idx >> 4) & (L_ - 1);
  int b = (int)(idx >> 16);
  float4 o = make_float4(0.f, 0.f, 0.f, 0.f);
  #pragma unroll
  for (int r = 0; r < R_; ++r) {
    float m = wred[(b * R_ + r) * 2];
    float sinv = 1.0f / wred[(b * R_ + r) * 2 + 1];
    float w = __expf(lse_s[((size_t)b * R_ + r) * L_ + l] - m) * sinv;
    ushort4 a = *(const ushort4*)(att + ((((size_t)b * R_ + r) * L_ + l) * 16 + d4) * 4);
    o.x += w * bf2f(a.x); o.y += w * bf2f(a.y);
    o.z += w * bf2f(a.z); o.w += w * bf2f(a.w);
  }
  ((float4*)out)[idx] = o;
}

extern "C" void kernel_launch(void* const* d_in, const int* in_sizes, int n_in,
                              void* d_out, int out_size, void* d_ws, size_t ws_size,
                              hipStream_t stream) {
  const float* query = (const float*)d_in[0];
  const float* value = (const float*)d_in[1];
  const float* rm    = (const float*)d_in[2];
  (void)in_sizes; (void)n_in; (void)out_size; (void)ws_size;

  char* ws = (char*)d_ws;
  const size_t ATT_BYTES = (size_t)B_ * R_ * L_ * DK_ * 2;  // 32 MiB (bf16)
  const size_t MB = 1048576;
  unsigned short* att        = (unsigned short*)ws;
  int*            bucket     = (int*)(ws + ATT_BYTES);
  int*            sorted_pos = (int*)(ws + ATT_BYTES + 1 * MB);
  unsigned char*  cpack      = (unsigned char*)(ws + ATT_BYTES + 2 * MB);
  float*          lse_s      = (float*)(ws + ATT_BYTES + 3 * MB);
  float*          wred       = (float*)(ws + ATT_BYTES + 4 * MB);
  float* out = (float*)d_out;

  hash_kernel<<<256, 256, 0, stream>>>(query, rm, bucket);
  sort_kernel<<<B_ * R_, 1024, 0, stream>>>(bucket, sorted_pos, cpack);
  attn_kernel<<<B_ * R_ * NB_, 256, 0, stream>>>(query, value, sorted_pos, bucket,
                                                 (const int*)cpack, att, lse_s);
  lsered_kernel<<<B_ * R_, 256, 0, stream>>>(lse_s, wred);
  combine_kernel<<<(B_ * L_ * 16) / 256, 256, 0, stream>>>(att, lse_s, wred, out);
}